// Round 1
// baseline (641.826 us; speedup 1.0000x reference)
//
#include <hip/hip_runtime.h>

#define NCOLS 65536
#define NROWS 256
#define HID 64
#define COLS_PER_BLOCK 4096
#define THREADS 1024
#define ROWS_PER_BLOCK 16

typedef float v2f __attribute__((ext_vector_type(2)));

__device__ __forceinline__ float pade_tanh(float x) {
    x = fminf(fmaxf(x, -16.f), 16.f);
    float xx = x * x;
    float num = x * fmaf(xx + 105.f, xx, 945.f);
    float den = fmaf(fmaf(xx, 15.f, 420.f), xx, 945.f);
    float r = num * __builtin_amdgcn_rcpf(den);
    return fminf(fmaxf(r, -1.f), 1.f);
}

__device__ __forceinline__ v2f pade_tanh2(v2f x) {
    x.x = fminf(fmaxf(x.x, -16.f), 16.f);
    x.y = fminf(fmaxf(x.y, -16.f), 16.f);
    v2f xx = x * x;
    v2f num = x * ((xx + 105.f) * xx + 945.f);
    v2f den = (xx * 15.f + 420.f) * xx + 945.f;
    v2f r;
    r.x = num.x * __builtin_amdgcn_rcpf(den.x);
    r.y = num.y * __builtin_amdgcn_rcpf(den.y);
    r.x = fminf(fmaxf(r.x, -1.f), 1.f);
    r.y = fminf(fmaxf(r.y, -1.f), 1.f);
    return r;
}

__global__ __launch_bounds__(THREADS, 4) void soen_kernel(
    const float* __restrict__ phi, const float* __restrict__ s,
    const float* __restrict__ i_b, const float* __restrict__ w1,
    const float* __restrict__ b1, const float* __restrict__ w2,
    const float* __restrict__ b2, const int* __restrict__ func_idx,
    float* __restrict__ out)
{
    __shared__ unsigned long long sbuf[THREADS];
    __shared__ unsigned short list[COLS_PER_BLOCK];
    __shared__ float4 wpack[HID];   // {w1[0][j], w1[1][j], w1[2][j], b1[j]}
    __shared__ float w2s[HID];

    const int t = threadIdx.x;
    const int colbase = blockIdx.x * COLS_PER_BLOCK;
    const int rowbase = blockIdx.y * ROWS_PER_BLOCK;

    if (t < HID) {
        wpack[t] = make_float4(w1[t], w1[HID + t], w1[2 * HID + t], b1[t]);
        w2s[t] = w2[t];
    }

    // ---- classify 4 columns per thread, block-wide stable partition by class ----
    int4 fi = ((const int4*)(func_idx + colbase))[t];
    const int cls4[4] = {fi.x, fi.y, fi.z, fi.w};
    unsigned long long mine = (1ULL << (16 * cls4[0])) + (1ULL << (16 * cls4[1]))
                            + (1ULL << (16 * cls4[2])) + (1ULL << (16 * cls4[3]));
    sbuf[t] = mine;
    __syncthreads();
    for (int st = 1; st < THREADS; st <<= 1) {
        unsigned long long v = (t >= st) ? sbuf[t - st] : 0ULL;
        __syncthreads();
        sbuf[t] += v;
        __syncthreads();
    }
    const unsigned long long tot = sbuf[THREADS - 1];
    const unsigned long long excl = sbuf[t] - mine;
    unsigned base[4];
    base[0] = 0;
    base[1] = (unsigned)(tot & 0xFFFF);
    base[2] = base[1] + (unsigned)((tot >> 16) & 0xFFFF);
    base[3] = base[2] + (unsigned)((tot >> 32) & 0xFFFF);
    unsigned ex[4] = {(unsigned)(excl & 0xFFFF), (unsigned)((excl >> 16) & 0xFFFF),
                      (unsigned)((excl >> 32) & 0xFFFF), (unsigned)((excl >> 48) & 0xFFFF)};
    unsigned run[4] = {0, 0, 0, 0};
    #pragma unroll
    for (int k = 0; k < 4; k++) {
        int c = cls4[k];
        unsigned pos = base[c] + ex[c] + run[c];
        run[c]++;
        list[pos] = (unsigned short)((4 * t + k) | (c << 12));
    }
    __syncthreads();

    const float b2v = b2[0];

    // ---- main work: each thread owns 4 class-sorted columns, loops over 16 rows ----
    #pragma unroll 1
    for (int k = 0; k < 4; k++) {
        const int e = list[4 * t + k];
        const int c = e >> 12;
        const int col = colbase + (e & 0xFFF);
        const float* pp = phi + (size_t)rowbase * NCOLS + col;
        const float* ss = s   + (size_t)rowbase * NCOLS + col;
        float*       po = out + (size_t)rowbase * NCOLS + col;

        if (c == 0) {
            #pragma unroll
            for (int r = 0; r < ROWS_PER_BLOCK; r++) {
                float ph = pp[(size_t)r * NCOLS];
                float sv = ss[(size_t)r * NCOLS];
                float p = ph - rintf(ph);
                po[(size_t)r * NCOLS] = fmaxf(fabsf(p) - sv, 0.f);
            }
        } else if (c == 1) {
            #pragma unroll
            for (int r = 0; r < ROWS_PER_BLOCK; r++) {
                float ph = pp[(size_t)r * NCOLS];
                float sv = ss[(size_t)r * NCOLS];
                float p = ph - rintf(ph);
                po[(size_t)r * NCOLS] = pade_tanh(p) * (1.f - sv);
            }
        } else if (c == 2) {
            #pragma unroll
            for (int r = 0; r < ROWS_PER_BLOCK; r++) {
                float ph = pp[(size_t)r * NCOLS];
                float sv = ss[(size_t)r * NCOLS];
                float p = ph - rintf(ph);
                po[(size_t)r * NCOLS] = __expf(-10.f * p * p) - sv;
            }
        } else {
            const float ib = i_b[col];
            #pragma unroll 1
            for (int rr = 0; rr < ROWS_PER_BLOCK; rr += 4) {
                float ph0 = pp[(size_t)(rr + 0) * NCOLS];
                float ph1 = pp[(size_t)(rr + 1) * NCOLS];
                float ph2 = pp[(size_t)(rr + 2) * NCOLS];
                float ph3 = pp[(size_t)(rr + 3) * NCOLS];
                float sv0 = ss[(size_t)(rr + 0) * NCOLS];
                float sv1 = ss[(size_t)(rr + 1) * NCOLS];
                float sv2 = ss[(size_t)(rr + 2) * NCOLS];
                float sv3 = ss[(size_t)(rr + 3) * NCOLS];
                v2f P01 = {ph0 - rintf(ph0), ph1 - rintf(ph1)};
                v2f P23 = {ph2 - rintf(ph2), ph3 - rintf(ph3)};
                v2f S01 = {sv0, sv1};
                v2f S23 = {sv2, sv3};
                v2f acc01 = {0.f, 0.f};
                v2f acc23 = {0.f, 0.f};
                #pragma unroll 4
                for (int j = 0; j < HID; j++) {
                    float4 w = wpack[j];
                    float cj = fmaf(ib, w.z, w.w);
                    v2f a01 = P01 * w.x + (S01 * w.y + cj);
                    v2f a23 = P23 * w.x + (S23 * w.y + cj);
                    v2f h01 = pade_tanh2(a01);
                    v2f h23 = pade_tanh2(a23);
                    float w2j = w2s[j];
                    acc01 += h01 * w2j;
                    acc23 += h23 * w2j;
                }
                po[(size_t)(rr + 0) * NCOLS] = acc01.x + b2v;
                po[(size_t)(rr + 1) * NCOLS] = acc01.y + b2v;
                po[(size_t)(rr + 2) * NCOLS] = acc23.x + b2v;
                po[(size_t)(rr + 3) * NCOLS] = acc23.y + b2v;
            }
        }
    }
}

extern "C" void kernel_launch(void* const* d_in, const int* in_sizes, int n_in,
                              void* d_out, int out_size, void* d_ws, size_t ws_size,
                              hipStream_t stream) {
    const float* phi      = (const float*)d_in[0];
    const float* s        = (const float*)d_in[1];
    const float* i_b      = (const float*)d_in[2];
    const float* w1       = (const float*)d_in[3];
    const float* b1       = (const float*)d_in[4];
    const float* w2       = (const float*)d_in[5];
    const float* b2       = (const float*)d_in[6];
    const int*   func_idx = (const int*)d_in[7];
    float* out = (float*)d_out;

    dim3 grid(NCOLS / COLS_PER_BLOCK, NROWS / ROWS_PER_BLOCK);
    soen_kernel<<<grid, dim3(THREADS), 0, stream>>>(phi, s, i_b, w1, b1, w2, b2,
                                                    func_idx, out);
}

// Round 2
// 325.251 us; speedup vs baseline: 1.9733x; 1.9733x over previous
//
#include <hip/hip_runtime.h>

#define NCOLS 65536
#define NROWS 256
#define HID 64
#define THREADS 256            // 4 waves
#define NWAVES 4
#define COLS_PER_BLOCK 256     // 64 cols per wave
#define ROWS_PER_BLOCK 64
#define CHUNK 8                // rows per MLP drain

typedef float v2f __attribute__((ext_vector_type(2)));

// Pade[5/4] tanh: x(945+105x^2+x^4)/(945+420x^2+15x^4), |err|<1e-3 everywhere
// (ratio -> x/15 for large |x|, clamped to +-1; no input clamp needed in f32).
__device__ __forceinline__ float pade_tanh(float x) {
    float xx = x * x;
    float num = x * fmaf(xx + 105.f, xx, 945.f);
    float den = fmaf(fmaf(xx, 15.f, 420.f), xx, 945.f);
    float r = num * __builtin_amdgcn_rcpf(den);
    return fminf(fmaxf(r, -1.f), 1.f);
}

__global__ __launch_bounds__(THREADS, 4) void soen_kernel(
    const float* __restrict__ phi, const float* __restrict__ s,
    const float* __restrict__ i_b, const float* __restrict__ w1,
    const float* __restrict__ b1, const float* __restrict__ w2,
    const float* __restrict__ b2, const int* __restrict__ func_idx,
    float* __restrict__ out)
{
    __shared__ float4 wpack[HID];                 // {w1[0][j],w1[1][j],w1[2][j],b1[j]}
    __shared__ float  w2s[HID];
    __shared__ unsigned char listc[NWAVES][64];   // compacted class-3 lane ids
    __shared__ float  ibc[NWAVES][64];            // their i_b values
    __shared__ v2f    queue[NWAVES][64 * CHUNK];  // (p, s) staging

    const int t = threadIdx.x;
    const int w = t >> 6;
    const int lane = t & 63;
    const int colbase = blockIdx.x * COLS_PER_BLOCK;
    const int rowbase = blockIdx.y * ROWS_PER_BLOCK;
    const int wcolbase = colbase + w * 64;
    const int col = wcolbase + lane;

    if (t < HID) {
        wpack[t] = make_float4(w1[t], w1[HID + t], w1[2 * HID + t], b1[t]);
        w2s[t] = w2[t];
    }
    __syncthreads();

    const int idx = func_idx[col];
    const float ib = i_b[col];
    const bool is3 = (idx == 3);
    const unsigned long long m3 = __ballot(is3);
    const int n3 = __popcll(m3);
    const int myci = __popcll(m3 & ((1ULL << lane) - 1ULL));
    if (is3) {
        listc[w][myci] = (unsigned char)lane;
        ibc[w][myci] = ib;
    }
    const float b2v = b2[0];

    for (int rc = 0; rc < ROWS_PER_BLOCK; rc += CHUNK) {
        const int r0 = rowbase + rc;

        // ---- cheap pass: fully coalesced; class-3 lanes stash (p,s) ----
        #pragma unroll
        for (int rr = 0; rr < CHUNK; rr++) {
            const size_t off = (size_t)(r0 + rr) * NCOLS + col;
            const float ph = phi[off];
            const float sv = s[off];
            const float p = ph - rintf(ph);
            const float g0 = fmaxf(fabsf(p) - sv, 0.f);
            const float g1 = pade_tanh(p) * (1.f - sv);
            const float g2 = __expf(-10.f * p * p) - sv;
            const float res = (idx == 0) ? g0 : (idx == 1) ? g1 : g2;
            if (!is3) {
                out[off] = res;
            } else {
                v2f q; q.x = p; q.y = sv;
                queue[w][myci * CHUNK + rr] = q;
            }
        }

        // ---- MLP drain: dense waves, 2 elements/lane packed ----
        const int P = n3 * CHUNK;
        for (int base = 0; base < P; base += 128) {
            const int ia = base + lane;
            const int ibn = base + 64 + lane;
            const bool va = ia < P;
            const bool vb = ibn < P;
            v2f qa = va ? queue[w][ia] : (v2f){0.f, 0.f};
            v2f qb = vb ? queue[w][ibn] : (v2f){0.f, 0.f};
            const int ca = va ? (ia >> 3) : 0;
            const int cb = vb ? (ibn >> 3) : 0;
            v2f P2; P2.x = qa.x; P2.y = qb.x;
            v2f S2; S2.x = qa.y; S2.y = qb.y;
            v2f IB; IB.x = ibc[w][ca]; IB.y = ibc[w][cb];
            v2f acc = {0.f, 0.f};
            #pragma unroll 4
            for (int j = 0; j < HID; j++) {
                const float4 W = wpack[j];
                v2f a = P2 * W.x + (S2 * W.y + (IB * W.z + W.w));
                v2f xx = a * a;
                v2f num = a * ((xx + 105.f) * xx + 945.f);
                v2f den = (xx * 15.f + 420.f) * xx + 945.f;
                v2f r;
                r.x = num.x * __builtin_amdgcn_rcpf(den.x);
                r.y = num.y * __builtin_amdgcn_rcpf(den.y);
                r.x = fminf(fmaxf(r.x, -1.f), 1.f);
                r.y = fminf(fmaxf(r.y, -1.f), 1.f);
                acc += r * w2s[j];
            }
            if (va) {
                const int row = r0 + (ia & (CHUNK - 1));
                const int cc = wcolbase + listc[w][ca];
                out[(size_t)row * NCOLS + cc] = acc.x + b2v;
            }
            if (vb) {
                const int row = r0 + (ibn & (CHUNK - 1));
                const int cc = wcolbase + listc[w][cb];
                out[(size_t)row * NCOLS + cc] = acc.y + b2v;
            }
        }
    }
}

extern "C" void kernel_launch(void* const* d_in, const int* in_sizes, int n_in,
                              void* d_out, int out_size, void* d_ws, size_t ws_size,
                              hipStream_t stream) {
    const float* phi      = (const float*)d_in[0];
    const float* s        = (const float*)d_in[1];
    const float* i_b      = (const float*)d_in[2];
    const float* w1       = (const float*)d_in[3];
    const float* b1       = (const float*)d_in[4];
    const float* w2       = (const float*)d_in[5];
    const float* b2       = (const float*)d_in[6];
    const int*   func_idx = (const int*)d_in[7];
    float* out = (float*)d_out;

    dim3 grid(NCOLS / COLS_PER_BLOCK, NROWS / ROWS_PER_BLOCK);
    soen_kernel<<<grid, dim3(THREADS), 0, stream>>>(phi, s, i_b, w1, b1, w2, b2,
                                                    func_idx, out);
}

// Round 3
// 248.136 us; speedup vs baseline: 2.5866x; 1.3108x over previous
//
#include <hip/hip_runtime.h>

#define NCOLS 65536
#define NROWS 256
#define HID 64
#define THREADS 256            // 4 waves
#define NWAVES 4
#define COLS_PER_BLOCK 256     // 64 cols per wave
#define ROWS_PER_BLOCK 32
#define QCAP 192               // ring capacity: qlen<=127 before append, +<=64 per row

typedef float v2f __attribute__((ext_vector_type(2)));

__global__ __launch_bounds__(THREADS, 8) void soen_kernel(
    const float* __restrict__ phi, const float* __restrict__ s,
    const float* __restrict__ i_b, const float* __restrict__ w1,
    const float* __restrict__ b1, const float* __restrict__ w2,
    const float* __restrict__ b2, const int* __restrict__ func_idx,
    float* __restrict__ out)
{
    __shared__ float4 wpk[HID];            // {2*w1[0][j], 2*w1[1][j], 2*w1[2][j], 2*b1[j]}
    __shared__ float  w2m2[HID];           // -2*w2[j]
    __shared__ float  qp[NWAVES][QCAP];    // queued p
    __shared__ float  qs[NWAVES][QCAP];    // queued s
    __shared__ unsigned short qm[NWAVES][QCAP]; // (row<<6)|lane
    __shared__ float  ibc[NWAVES][64];     // i_b per lane-column

    const int t = threadIdx.x;
    const int w = t >> 6;
    const int lane = t & 63;
    const int colbase = blockIdx.x * COLS_PER_BLOCK;
    const int rowbase = blockIdx.y * ROWS_PER_BLOCK;
    const int wcolbase = colbase + w * 64;
    const int col = wcolbase + lane;

    if (t < HID) {
        wpk[t] = make_float4(2.f * w1[t], 2.f * w1[HID + t], 2.f * w1[2 * HID + t],
                             2.f * b1[t]);
        w2m2[t] = -2.f * w2[t];
    }
    __syncthreads();

    const int idx = func_idx[col];
    const float ib = i_b[col];
    ibc[w][lane] = ib;
    const bool is3 = (idx == 3);
    const unsigned long long m3 = __ballot(is3);
    const int n3 = __popcll(m3);
    const int myci = __popcll(m3 & ((1ULL << lane) - 1ULL));

    const float b2v = b2[0];
    float sumb = b2v;                       // b2 + sum_j w2[j]
    #pragma unroll
    for (int j = 0; j < HID; j++) sumb -= 0.5f * w2m2[j];

    // drain 'cnt' (<=128) queued elements starting at ring position hd
    auto drain = [&](int hd, int cnt) {
        int i0 = hd + lane;        if (i0 >= QCAP) i0 -= QCAP;
        int i1 = hd + 64 + lane;   if (i1 >= QCAP) i1 -= QCAP;
        const bool v0 = lane < cnt;
        const bool v1 = (64 + lane) < cnt;
        const float p0 = qp[w][i0], s0 = qs[w][i0];
        const float p1 = qp[w][i1], s1 = qs[w][i1];
        const int m0 = qm[w][i0], m1 = qm[w][i1];
        v2f P2; P2.x = p0; P2.y = p1;
        v2f S2; S2.x = s0; S2.y = s1;
        v2f IB; IB.x = ibc[w][m0 & 63]; IB.y = ibc[w][m1 & 63];
        v2f acc0 = {0.f, 0.f};
        v2f acc1 = {0.f, 0.f};
        #pragma unroll 4
        for (int j = 0; j < HID; j += 2) {
            const float4 W0 = wpk[j];
            v2f A0 = P2 * W0.x + (S2 * W0.y + (IB * W0.z + W0.w));   // = 2*a
            v2f U0;
            U0.x = __builtin_amdgcn_rcpf(1.f + __expf(A0.x));
            U0.y = __builtin_amdgcn_rcpf(1.f + __expf(A0.y));
            acc0 += U0 * w2m2[j];
            const float4 W1 = wpk[j + 1];
            v2f A1 = P2 * W1.x + (S2 * W1.y + (IB * W1.z + W1.w));
            v2f U1;
            U1.x = __builtin_amdgcn_rcpf(1.f + __expf(A1.x));
            U1.y = __builtin_amdgcn_rcpf(1.f + __expf(A1.y));
            acc1 += U1 * w2m2[j + 1];
        }
        v2f acc = acc0 + acc1;
        if (v0) {
            const int row = rowbase + (m0 >> 6);
            out[(size_t)row * NCOLS + (wcolbase + (m0 & 63))] = sumb + acc.x;
        }
        if (v1) {
            const int row = rowbase + (m1 >> 6);
            out[(size_t)row * NCOLS + (wcolbase + (m1 & 63))] = sumb + acc.y;
        }
    };

    int head = 0, tail = 0, qlen = 0;

    #pragma unroll 2
    for (int r = 0; r < ROWS_PER_BLOCK; r++) {
        const size_t off = (size_t)(rowbase + r) * NCOLS + col;
        const float ph = phi[off];
        const float sv = s[off];
        const float p = ph - rintf(ph);          // v_rndne, half-to-even
        const float p2 = p * p;
        // g0
        const float g0 = fmaxf(fabsf(p) - sv, 0.f);
        // g1: tanh(p) for |p|<=0.5 via odd series, err<5e-4
        const float tp = p * fmaf(p2, fmaf(p2, 0.13333333f, -0.33333333f), 1.f);
        const float g1 = fmaf(-tp, sv, tp);
        // g2
        const float g2 = __expf(-10.f * p2) - sv;
        const float res = (idx == 0) ? g0 : (idx == 1) ? g1 : g2;
        if (!is3) {
            out[off] = res;
        } else {
            int pos = tail + myci; if (pos >= QCAP) pos -= QCAP;
            qp[w][pos] = p;
            qs[w][pos] = sv;
            qm[w][pos] = (unsigned short)((r << 6) | lane);
        }
        tail += n3; if (tail >= QCAP) tail -= QCAP;
        qlen += n3;
        if (qlen >= 128) {
            drain(head, 128);
            head += 128; if (head >= QCAP) head -= QCAP;
            qlen -= 128;
        }
    }
    if (qlen > 0) drain(head, qlen);
}

extern "C" void kernel_launch(void* const* d_in, const int* in_sizes, int n_in,
                              void* d_out, int out_size, void* d_ws, size_t ws_size,
                              hipStream_t stream) {
    const float* phi      = (const float*)d_in[0];
    const float* s        = (const float*)d_in[1];
    const float* i_b      = (const float*)d_in[2];
    const float* w1       = (const float*)d_in[3];
    const float* b1       = (const float*)d_in[4];
    const float* w2       = (const float*)d_in[5];
    const float* b2       = (const float*)d_in[6];
    const int*   func_idx = (const int*)d_in[7];
    float* out = (float*)d_out;

    dim3 grid(NCOLS / COLS_PER_BLOCK, NROWS / ROWS_PER_BLOCK);
    soen_kernel<<<grid, dim3(THREADS), 0, stream>>>(phi, s, i_b, w1, b1, w2, b2,
                                                    func_idx, out);
}